// Round 7
// baseline (722.195 us; speedup 1.0000x reference)
//
#include <hip/hip_runtime.h>
#include <hip/hip_bf16.h>
#include <math.h>

#define N 4
#define C 256
#define H 128
#define W 128
#define CO 288        // GROUP * K * K = 32 * 9
#define OH 126
#define OW 126
#define GROUP 32
#define CPG 8
#define EPS 1e-5f

#define HW (OH*OW)          // 15876
#define XSLICE (H*W)        // 16384
#define XNSTRIDE (C*H*W)    // 4194304
#define SNSTRIDE (CO*HW)    // 4572288
#define LONSTRIDE (C*HW)    // 4064256
#define WSTRIDE (CO*256)    // 73728 u16 per shift s
#define WTOT (9*CO*256)     // 663552 u16 per table (wlT = whT + WTOT)
#define XTOT (N*H*W*C)      // 16777216 u16 per table (xl = xh + XTOT)

typedef unsigned short u16;
typedef __attribute__((ext_vector_type(8))) short short8;
typedef __attribute__((ext_vector_type(4))) float float4v;

__device__ inline u16 f2bf(float v) {
    __hip_bfloat16 b = __float2bfloat16(v);
    return __builtin_bit_cast(u16, b);
}
__device__ inline float bf2f(u16 u) {
    __hip_bfloat16 b = __builtin_bit_cast(__hip_bfloat16, u);
    return __bfloat162float(b);
}

// ---------------- Prep: split x into bf16 hi/lo, transpose to NHWC ----------------
// xh/xl layout: [n][h][w][ci] (ci contiguous); xl MUST be at xh + XTOT.
__global__ __launch_bounds__(256) void split_x_kernel(const float* __restrict__ x,
                                                      u16* __restrict__ xh,
                                                      u16* __restrict__ xl) {
    const int ci = threadIdx.x;          // 0..255
    const int w0 = blockIdx.x * 8;       // 16 groups
    const int h  = blockIdx.y;
    const int n  = blockIdx.z;
    const float* src = x + ((size_t)(n*C + ci)*H + h)*W + w0;
    float4 v0 = *(const float4*)src;
    float4 v1 = *(const float4*)(src + 4);
    float vals[8] = {v0.x, v0.y, v0.z, v0.w, v1.x, v1.y, v1.z, v1.w};
    size_t obase = ((size_t)(n*H + h)*W + w0)*C + ci;
    #pragma unroll
    for (int dw = 0; dw < 8; ++dw) {
        float v = vals[dw];
        u16 hb = f2bf(v);
        xh[obase + (size_t)dw*C] = hb;
        xl[obase + (size_t)dw*C] = f2bf(v - bf2f(hb));
    }
}

// ---------------- Prep: split w into bf16 hi/lo, layout [s][co][ci] ----------------
__global__ __launch_bounds__(256) void split_w_kernel(const float* __restrict__ wgt,
                                                      u16* __restrict__ whT,
                                                      u16* __restrict__ wlT) {
    const int i = blockIdx.x*256 + threadIdx.x;  // < 9*288*256 = 663552
    const int ci = i & 255;
    const int co = (i >> 8) % CO;
    const int s  = i / (CO*256);
    float v = wgt[(size_t)co*(C*9) + (size_t)ci*9 + s];
    u16 hb = f2bf(v);
    whT[i] = hb;
    wlT[i] = f2bf(v - bf2f(hb));
}

// ---------------- Conv 3x3 VALID via bf16 MFMA implicit GEMM ----------------
// Grid (2, 63, N), block 256 = 4 waves.
// Block: 2 output rows x 64 positions x 288 co.  Wave = 1 row x 64 pos x 144 co,
// acc[4 mt][9 j] float4.
//
// B (weights) are NOT staged in LDS: the w tables (2.6 MB) are L2-resident, and
// each B fragment is a 16 B chunk of a 64 B-aligned window of whT[s][co][ci] --
// a per-lane global_load_dwordx4 is cache-line clean (4 q-lanes share each 64 B
// line; duplicate wr-wave reads hit L1). This removes all per-shift barriers.
//
// NOTE (round-6 fix): the shift loop is `#pragma unroll 1` -- fully unrolling it
// created a single ~1200-op barrier-free scheduling region (972 MFMA + 162
// global loads) that plausibly blew up hipcc scheduling/regalloc (container
// died before any pytest verdict in rounds 5/6). One shift per region
// ({8 ds_read + 18 global_load + 108 MFMA}) matches the region size every
// previously-passing kernel compiled fine. FP accumulation order per acc[mt][j]
// is unchanged (sequential s; ah*bh, al*bh, ah*bl within a shift).
//
// xs (activations) in LDS, double-buffered: next-ci0 loads issue at the top of
// the current ci0 iteration and drain at the single per-ci0 barrier, having
// aged through 9 shifts of compute. 9 barriers per block total.
__global__ __launch_bounds__(256, 2) void conv_mfma_kernel(const u16* __restrict__ xh,
                                                           const u16* __restrict__ whT,
                                                           float* __restrict__ sigma) {
    // xs chunk c = spq*264 + row*66 + col (spq = sp*4+q, row 0..3, col 0..65)
    // u16 index = buf*16896 + c*8
    __shared__ __align__(16) u16 xs[2*8*4*66*8];     // 67584 B -> 2 blocks/CU

    const int tid  = threadIdx.x;
    const int wave = tid >> 6;
    const int lane = tid & 63;
    const int m16  = lane & 15;
    const int q    = lane >> 4;
    const int wr   = wave & 1;      // output row within block
    const int wc   = wave >> 1;     // co half (144 each)
    const int ow0  = blockIdx.x * 64;
    const int oh0  = blockIdx.y * 2;
    const int n    = blockIdx.z;

    // ---- x staging: 2112 chunks; issue idx = 4t+wave, t<9, idx<33 ----
    int xoff[9];
    #pragma unroll
    for (int t = 0; t < 9; ++t) {
        int c = (4*t + wave)*64 + lane;
        if (c > 2111) c = 2111;                  // unused (guarded at issue)
        const int spq = c / 264;
        const int rem = c - spq*264;
        const int row = rem / 66;
        const int col = rem - row*66;
        int gc = ow0 + col; if (gc > W-1) gc = W-1;   // clamp feeds discarded outputs
        xoff[t] = (spq >> 2)*XTOT + ((n*H + oh0 + row)*W + gc)*C + (spq & 3)*8;
    }

    // ---- A fragment read offset (u16 units, within one buffer) ----
    const int aoff = (q*264 + wr*66 + m16)*8;    // + ky*528 + kx*8 + mt*128 ; lo +8448

    // ---- B global base: per-lane pointer into whT[s][co][ci] ----
    // tile j: co = wc*144 + j*16 + m16, k = ci0 + q*8..+8  -> 16B load
    const u16* wg = whT + (size_t)((wc*144 + m16)*256 + q*8);

    float4v acc[4][9];
    #pragma unroll
    for (int mt = 0; mt < 4; ++mt)
        #pragma unroll
        for (int j = 0; j < 9; ++j) acc[mt][j] = (float4v)(0.f);

    // ---- prologue: stage xs(ci0=0) into buf 0, drain ----
    #pragma unroll
    for (int t = 0; t < 9; ++t)
        if (t < 8 || wave == 0)
            __builtin_amdgcn_global_load_lds((const uint*)(xh + xoff[t]),
                                             (uint*)(xs + (4*t + wave)*512), 16, 0, 0);
    __syncthreads();

    int buf = 0;
    for (int ci0 = 0; ci0 < C; ci0 += 32) {
        // issue next-ci0 x loads into buf^1 now; they drain at this
        // iteration's ending barrier after aging through 9 shifts of compute
        const int nci = ci0 + 32;
        if (nci < C) {
            #pragma unroll
            for (int t = 0; t < 9; ++t)
                if (t < 8 || wave == 0)
                    __builtin_amdgcn_global_load_lds(
                        (const uint*)(xh + xoff[t] + nci),
                        (uint*)(xs + (buf^1)*16896 + (4*t + wave)*512), 16, 0, 0);
        }

        #pragma unroll 1
        for (int s = 0; s < 9; ++s) {
            const int ky = s / 3;
            const int kx = s - 3*ky;
            const u16* wp = wg + (size_t)s*WSTRIDE + ci0;

            const int ab = buf*16896 + aoff + ky*528 + kx*8;
            short8 ah0 = *(const short8*)&xs[ab];
            short8 ah1 = *(const short8*)&xs[ab + 128];
            short8 ah2 = *(const short8*)&xs[ab + 256];
            short8 ah3 = *(const short8*)&xs[ab + 384];
            short8 al0 = *(const short8*)&xs[ab + 8448];
            short8 al1 = *(const short8*)&xs[ab + 8448 + 128];
            short8 al2 = *(const short8*)&xs[ab + 8448 + 256];
            short8 al3 = *(const short8*)&xs[ab + 8448 + 384];
            #pragma unroll
            for (int j = 0; j < 9; ++j) {
                short8 bh = *(const short8*)(wp + j*4096);
                short8 bl = *(const short8*)(wp + WTOT + j*4096);
                acc[0][j] = __builtin_amdgcn_mfma_f32_16x16x32_bf16(ah0, bh, acc[0][j], 0, 0, 0);
                acc[1][j] = __builtin_amdgcn_mfma_f32_16x16x32_bf16(ah1, bh, acc[1][j], 0, 0, 0);
                acc[2][j] = __builtin_amdgcn_mfma_f32_16x16x32_bf16(ah2, bh, acc[2][j], 0, 0, 0);
                acc[3][j] = __builtin_amdgcn_mfma_f32_16x16x32_bf16(ah3, bh, acc[3][j], 0, 0, 0);
                acc[0][j] = __builtin_amdgcn_mfma_f32_16x16x32_bf16(al0, bh, acc[0][j], 0, 0, 0);
                acc[1][j] = __builtin_amdgcn_mfma_f32_16x16x32_bf16(al1, bh, acc[1][j], 0, 0, 0);
                acc[2][j] = __builtin_amdgcn_mfma_f32_16x16x32_bf16(al2, bh, acc[2][j], 0, 0, 0);
                acc[3][j] = __builtin_amdgcn_mfma_f32_16x16x32_bf16(al3, bh, acc[3][j], 0, 0, 0);
                acc[0][j] = __builtin_amdgcn_mfma_f32_16x16x32_bf16(ah0, bl, acc[0][j], 0, 0, 0);
                acc[1][j] = __builtin_amdgcn_mfma_f32_16x16x32_bf16(ah1, bl, acc[1][j], 0, 0, 0);
                acc[2][j] = __builtin_amdgcn_mfma_f32_16x16x32_bf16(ah2, bl, acc[2][j], 0, 0, 0);
                acc[3][j] = __builtin_amdgcn_mfma_f32_16x16x32_bf16(ah3, bl, acc[3][j], 0, 0, 0);
            }
        }

        __syncthreads();   // buf readers done + buf^1 loads drained (aged 9 shifts)
        buf ^= 1;
    }

    // store: D[row=q*4+r][col=m16]; pos = mt*16+q*4+r, co = wc*144+j*16+m16
    #pragma unroll
    for (int mt = 0; mt < 4; ++mt) {
        const int posb = mt*16 + q*4;
        #pragma unroll
        for (int j = 0; j < 9; ++j) {
            const int co = wc*144 + j*16 + m16;
            float* dst = sigma + (size_t)n*SNSTRIDE + (size_t)co*HW + (oh0 + wr)*OW;
            #pragma unroll
            for (int r = 0; r < 4; ++r) {
                const int ow = ow0 + posb + r;
                if (ow < OW) dst[ow] = acc[mt][j][r];
            }
        }
    }
}

// ---------------- Per-channel mean/var over (N, OH, OW) ----------------
__global__ __launch_bounds__(1024) void stats_kernel(const float* __restrict__ sigma,
                                                     const float* __restrict__ gamma,
                                                     const float* __restrict__ beta,
                                                     float* __restrict__ coef) {
    const int c = blockIdx.x;
    float sum = 0.f, sq = 0.f;
    for (int n = 0; n < N; ++n) {
        const float* sp = sigma + (size_t)n*SNSTRIDE + (size_t)c*HW;
        for (int i = threadIdx.x; i < HW; i += 1024) {
            float v = sp[i];
            sum += v; sq += v * v;
        }
    }
    for (int off = 32; off > 0; off >>= 1) {
        sum += __shfl_down(sum, off, 64);
        sq  += __shfl_down(sq,  off, 64);
    }
    __shared__ float ls[16], lq[16];
    const int wid = threadIdx.x >> 6, lane = threadIdx.x & 63;
    if (lane == 0) { ls[wid] = sum; lq[wid] = sq; }
    __syncthreads();
    if (threadIdx.x == 0) {
        float S = 0.f, Q = 0.f;
        #pragma unroll
        for (int i = 0; i < 16; ++i) { S += ls[i]; Q += lq[i]; }
        const float cnt = (float)(N * HW);
        float mean = S / cnt;
        float var  = Q / cnt - mean * mean;
        float a = gamma[c] * rsqrtf(var + EPS);
        coef[c]      = a;
        coef[CO + c] = beta[c] - mean * a;
    }
}

// ---------------- Fused normalize + softmax(288) + grouped dynamic 3x3 ----------------
// Single pass: no max-subtraction (normalized s -> |s| small, exp is fp32-safe),
// divide deferred: outlo holds sum_p x*e, per-position sum(e) stored in sums[];
// upsample divides each tap. One sigma sweep instead of three.
__global__ __launch_bounds__(256) void fuse_kernel(const float* __restrict__ x,
                                                   const float* __restrict__ sigma,
                                                   const float* __restrict__ coef,
                                                   float* __restrict__ outlo,
                                                   float* __restrict__ sums) {
    __shared__ float a[CO], b[CO];
    for (int i = threadIdx.x; i < CO; i += 256) {
        a[i] = coef[i];
        b[i] = coef[CO + i];
    }
    __syncthreads();

    const int gpos = blockIdx.x * 256 + threadIdx.x;
    if (gpos >= N * HW) return;
    const int n  = gpos / HW;
    const int hw = gpos - n * HW;
    const int oh = hw / OW;
    const int ow = hw - oh * OW;

    const float* sp = sigma + (size_t)n * SNSTRIDE + hw;
    const float* xb = x + (size_t)n * XNSTRIDE + oh * W + ow;
    float* ob = outlo + (size_t)n * LONSTRIDE + hw;

    float sum = 0.f;
    for (int g = 0; g < GROUP; ++g) {
        float acc[CPG];
        #pragma unroll
        for (int c = 0; c < CPG; ++c) acc[c] = 0.f;
        #pragma unroll
        for (int p = 0; p < 9; ++p) {
            const int ch = g * 9 + p;
            float s = sp[(size_t)ch * HW] * a[ch] + b[ch];
            float e = __expf(s);
            sum += e;
            const float* xr = xb + (size_t)(g * CPG) * XSLICE + (p / 3) * W + (p % 3);
            #pragma unroll
            for (int c = 0; c < CPG; ++c)
                acc[c] += xr[(size_t)c * XSLICE] * e;
        }
        #pragma unroll
        for (int c = 0; c < CPG; ++c)
            ob[(size_t)(g * CPG + c) * HW] = acc[c];
    }
    sums[gpos] = sum;
}

// ---------------- Bilinear align-corners upsample 126 -> 128 (+ softmax divide) ----
__global__ __launch_bounds__(256) void upsample_kernel(const float* __restrict__ lo,
                                                       const float* __restrict__ sums,
                                                       float* __restrict__ out) {
    const int idx = blockIdx.x * 256 + threadIdx.x;
    const int xi = idx & (W - 1);
    const int yi = (idx >> 7) & (H - 1);
    const int nc = idx >> 14;
    const int n  = nc >> 8;              // C = 256

    const float scale = 125.0f / 127.0f;
    const float sy = yi * scale;
    const float sx = xi * scale;
    int y0 = (int)sy;
    int x0 = (int)sx;
    float wy = sy - (float)y0;
    float wx = sx - (float)x0;
    int y1 = min(y0 + 1, OH - 1);
    int x1 = min(x0 + 1, OW - 1);

    const float* p  = lo + (size_t)nc * HW;
    const float* ps = sums + (size_t)n * HW;
    float v00 = p[y0 * OW + x0] / ps[y0 * OW + x0];
    float v01 = p[y0 * OW + x1] / ps[y0 * OW + x1];
    float v10 = p[y1 * OW + x0] / ps[y1 * OW + x0];
    float v11 = p[y1 * OW + x1] / ps[y1 * OW + x1];
    float top = v00 * (1.f - wx) + v01 * wx;
    float bot = v10 * (1.f - wx) + v11 * wx;
    out[idx] = top * (1.f - wy) + bot * wy;
}

extern "C" void kernel_launch(void* const* d_in, const int* in_sizes, int n_in,
                              void* d_out, int out_size, void* d_ws, size_t ws_size,
                              hipStream_t stream) {
    const float* x      = (const float*)d_in[0];
    const float* conv_w = (const float*)d_in[1];
    const float* gamma  = (const float*)d_in[2];
    const float* beta   = (const float*)d_in[3];
    float* out = (float*)d_out;
    float* ws  = (float*)d_ws;

    // workspace (floats):
    //   sigma : [0, 18289152)
    //   coef  : [18289152, +1024)
    //   outlo : [18290176, +16257024)   -- ALIASED with xh/xl (prep+conv finish first)
    //   sums  : aliased over whT (dead after conv, written by fuse, read by upsample)
    float* sigma = ws;
    float* coef  = ws + 18289152;
    float* outlo = ws + 18290176;
    u16* xhp = (u16*)(ws + 18290176);               // 16777216 u16 = 33.5 MB
    u16* xlp = xhp + (size_t)XTOT;                  // adjacent: xl = xh + XTOT
    u16* whT = xlp + (size_t)XTOT;                  // 663552 u16
    u16* wlT = whT + (size_t)WTOT;                  // adjacent: wl = wh + WTOT
    float* sums = (float*)whT;                      // 63504 floats, fits in w region
    // total ws usage ~143 MB

    split_x_kernel<<<dim3(16, 128, 4), 256, 0, stream>>>(x, xhp, xlp);
    split_w_kernel<<<(9*CO*256)/256, 256, 0, stream>>>(conv_w, whT, wlT);

    conv_mfma_kernel<<<dim3(2, 63, N), 256, 0, stream>>>(xhp, whT, sigma);

    stats_kernel<<<CO, 1024, 0, stream>>>(sigma, gamma, beta, coef);

    fuse_kernel<<<(N * HW + 255) / 256, 256, 0, stream>>>(x, sigma, coef, outlo, sums);

    upsample_kernel<<<(N * C * H * W) / 256, 256, 0, stream>>>(outlo, sums, out);
}